// Round 6
// baseline (585.058 us; speedup 1.0000x reference)
//
#include <hip/hip_runtime.h>

typedef _Float16 half8 __attribute__((ext_vector_type(8)));
typedef _Float16 half4v __attribute__((ext_vector_type(4)));
typedef float f32x4 __attribute__((ext_vector_type(4)));

__device__ __forceinline__ void gld_lds16(const void* g, void* l) {
  __builtin_amdgcn_global_load_lds((const __attribute__((address_space(1))) void*)g,
                                   (__attribute__((address_space(3))) void*)l, 16, 0, 0);
}

// ---------------- fp32 -> f16 convert (vectorized) ----------------
__global__ void cvt_f32_f16(const float* __restrict__ src, _Float16* __restrict__ dst, int n4) {
  int i = blockIdx.x * 256 + threadIdx.x;
  if (i < n4) {
    float4 v = ((const float4*)src)[i];
    half4v h;
    h.x = (_Float16)v.x; h.y = (_Float16)v.y; h.z = (_Float16)v.z; h.w = (_Float16)v.w;
    ((half4v*)dst)[i] = h;
  }
}

// ---------------- mask tile flags: flag=1 iff no zeros in 128x64 tile ----------------
__global__ void mask_flags_k(const int* __restrict__ mask, unsigned char* __restrict__ flags) {
  int qt = blockIdx.x, kt = blockIdx.y; // 16 x 32
  __shared__ int allv;
  if (threadIdx.x == 0) allv = 1;
  __syncthreads();
  int ok = 1;
  for (int idx = threadIdx.x; idx < 128 * 64; idx += 256) {
    int qr = qt * 128 + (idx >> 6);
    int kc = kt * 64 + (idx & 63);
    ok &= (mask[(size_t)qr * 2048 + kc] != 0);
  }
  if (!ok) atomicAnd(&allv, 0);
  __syncthreads();
  if (threadIdx.x == 0) flags[qt * 32 + kt] = (unsigned char)allv;
}

// ---------------- GEMM: y[M=8192,N=1024] = A[M,1024] @ B[N,1024]^T + bias, * oscale ----------
// LAYOUT 0: f16 heads [b,h,s,d]   LAYOUT 1: f16 V^T [b,h,d,s]   LAYOUT 2: fp32 [row,col]
// XCD-aware remap (T1): linear wg -> xcd = wg&7 owns an 8x8 (m,n) tile block so A-panels
// and B-panels are shared within one XCD's L2 (working set 4MB). Bijective for 512 blocks.
template <int LAYOUT>
__global__ __launch_bounds__(256, 2) void gemm_k(const _Float16* __restrict__ A,
                                                 const _Float16* __restrict__ B,
                                                 const float* __restrict__ bias,
                                                 void* __restrict__ dst, float oscale) {
  __shared__ _Float16 Alds[128][32];
  __shared__ _Float16 Blds[128][32];
  int tid = threadIdx.x, w = tid >> 6, l = tid & 63;
  int lm = l & 15, lg = l >> 4;
  int wm = w >> 1, wn = w & 1;
  int wg = blockIdx.y * 8 + blockIdx.x;  // linear id, x fastest
  int xcd = wg & 7, j = wg >> 3;
  int m0 = (xcd * 8 + (j >> 3)) * 128, n0 = (j & 7) * 128;
  f32x4 acc[4][4] = {};
  for (int k0 = 0; k0 < 1024; k0 += 32) {
#pragma unroll
    for (int c = 0; c < 2; ++c) {
      int o = w * 2048 + c * 1024 + l * 16;  // byte offset within 8KB tile
      int row = o >> 6;
      int kb = (o & 63) >> 1;  // f16 element offset within row
      gld_lds16(A + (size_t)(m0 + row) * 1024 + k0 + kb, (char*)&Alds[0][0] + w * 2048 + c * 1024);
      gld_lds16(B + (size_t)(n0 + row) * 1024 + k0 + kb, (char*)&Blds[0][0] + w * 2048 + c * 1024);
    }
    __syncthreads();
    half8 af[4], bf[4];
#pragma unroll
    for (int m = 0; m < 4; ++m) af[m] = *(const half8*)&Alds[wm * 64 + m * 16 + lm][lg * 8];
#pragma unroll
    for (int n = 0; n < 4; ++n) bf[n] = *(const half8*)&Blds[wn * 64 + n * 16 + lm][lg * 8];
#pragma unroll
    for (int m = 0; m < 4; ++m)
#pragma unroll
      for (int n = 0; n < 4; ++n)
        acc[m][n] = __builtin_amdgcn_mfma_f32_16x16x32_f16(af[m], bf[n], acc[m][n], 0, 0, 0);
    __syncthreads();
  }
  float bs[4];
#pragma unroll
  for (int n = 0; n < 4; ++n) bs[n] = bias[n0 + wn * 64 + n * 16 + lm];
#pragma unroll
  for (int m = 0; m < 4; ++m) {
#pragma unroll
    for (int n = 0; n < 4; ++n) {
      int colg = n0 + wn * 64 + n * 16 + lm;
#pragma unroll
      for (int j2 = 0; j2 < 4; ++j2) {
        int rowg = m0 + wm * 64 + m * 16 + lg * 4 + j2;
        float v = (acc[m][n][j2] + bs[n]) * oscale;
        if constexpr (LAYOUT == 0) {
          int b = rowg >> 11, s = rowg & 2047, h = colg >> 6, d = colg & 63;
          ((_Float16*)dst)[((size_t)(b * 16 + h) * 2048 + s) * 64 + d] = (_Float16)v;
        } else if constexpr (LAYOUT == 1) {
          int b = rowg >> 11, s = rowg & 2047, h = colg >> 6, d = colg & 63;
          ((_Float16*)dst)[((size_t)(b * 16 + h) * 64 + d) * 2048 + s] = (_Float16)v;
        } else {
          ((float*)dst)[(size_t)rowg * 1024 + colg] = v;
        }
      }
    }
  }
}

// ---------------- flash attention ----------------
// grid (64 bh, 16 qtiles) — x = bh so linear%8 = bh%8: all 16 q-tile blocks of one
// (b,h) land on the same XCD (T1). 256 threads = 4 waves; wave w owns 32 q-rows.
// Q pre-scaled by 0.125*log2(e) in its GEMM epilogue -> softmax in log2 domain.
// Swapped QK^T: sT = mfma(K, Q), lane owns q-row lm.
// ROUND 6: body split into two sequential per-m phases so the live set fits 128 VGPRs
// (round 5 spilled at the 64-VGPR cap from launch_bounds(256,4): all pipes <30%,
// duration insensitive to L3 warmth). kf/vf are per-n transients now; K/V loads issued
// twice per tile but all 4 waves share addresses -> L1-hot on the second pass.
__global__ __launch_bounds__(256, 4) void attn_k(const _Float16* __restrict__ Q,
                                                 const _Float16* __restrict__ K,
                                                 const _Float16* __restrict__ Vt,
                                                 const unsigned char* __restrict__ flags,
                                                 const int* __restrict__ mask,
                                                 _Float16* __restrict__ out) {
  __shared__ __align__(16) char Plds[4][4096];  // per-wave 32 rows x 128B, XOR-swizzled
  int bh = blockIdx.x, qt = blockIdx.y;
  int tid = threadIdx.x, w = tid >> 6, l = tid & 63;
  int lm = l & 15, lg = l >> 4;
  const size_t hb = (size_t)bh * (2048 * 64);
  int q0 = qt * 128 + w * 32;

  half8 qf[2][2];
#pragma unroll
  for (int m = 0; m < 2; ++m)
#pragma unroll
    for (int kk = 0; kk < 2; ++kk)
      qf[m][kk] = *(const half8*)&Q[hb + (size_t)(q0 + m * 16 + lm) * 64 + kk * 32 + lg * 8];

  f32x4 oacc[2][4] = {};
  float mrun[2] = {-1e30f, -1e30f};
  float lrun[2] = {0.f, 0.f};

  for (int t = 0; t < 32; ++t) {
    int flg = flags[qt * 32 + t];
#pragma unroll
    for (int m = 0; m < 2; ++m) {
      // ---- QK^T for this m (kf transient per n) ----
      f32x4 sTm[4];
      f32x4 z = {0.f, 0.f, 0.f, 0.f};
#pragma unroll
      for (int n = 0; n < 4; ++n) {
        half8 kf0 = *(const half8*)&K[hb + (size_t)(t * 64 + n * 16 + lm) * 64 + 0 * 32 + lg * 8];
        half8 kf1 = *(const half8*)&K[hb + (size_t)(t * 64 + n * 16 + lm) * 64 + 1 * 32 + lg * 8];
        __builtin_amdgcn_s_setprio(1);
        sTm[n] = __builtin_amdgcn_mfma_f32_16x16x32_f16(kf0, qf[m][0], z, 0, 0, 0);
        sTm[n] = __builtin_amdgcn_mfma_f32_16x16x32_f16(kf1, qf[m][1], sTm[n], 0, 0, 0);
        __builtin_amdgcn_s_setprio(0);
      }
      if (!flg) {  // slow path: per-element mask (not taken for all-ones mask)
#pragma unroll
        for (int n = 0; n < 4; ++n)
#pragma unroll
          for (int j = 0; j < 4; ++j) {
            int qr = q0 + m * 16 + lm;
            int kc = t * 64 + n * 16 + lg * 4 + j;
            if (mask[(size_t)qr * 2048 + kc] == 0) sTm[n][j] = -1e30f;
          }
      }
      // ---- softmax (lane owns q-row; in-reg tree + 2 shfl) ----
      float mx[4], ps[4];
#pragma unroll
      for (int n = 0; n < 4; ++n)
        mx[n] = fmaxf(fmaxf(sTm[n][0], sTm[n][1]), fmaxf(sTm[n][2], sTm[n][3]));
      float pmax = fmaxf(fmaxf(mx[0], mx[1]), fmaxf(mx[2], mx[3]));
      pmax = fmaxf(pmax, __shfl_xor(pmax, 16, 64));
      pmax = fmaxf(pmax, __shfl_xor(pmax, 32, 64));
      float mnew = fmaxf(mrun[m], pmax);
      float alpha = exp2f(mrun[m] - mnew);
      int row = m * 16 + lm;
#pragma unroll
      for (int n = 0; n < 4; ++n) {
        half4v p4;
        float pp[4];
#pragma unroll
        for (int j = 0; j < 4; ++j) {
          pp[j] = exp2f(sTm[n][j] - mnew);  // log2-domain (L2E folded into Q)
          p4[j] = (_Float16)pp[j];
        }
        ps[n] = (pp[0] + pp[1]) + (pp[2] + pp[3]);
        int byte = row * 128 + (((n * 32 + lg * 8)) ^ ((row & 7) << 4));
        *(half4v*)(&Plds[w][byte]) = p4;
      }
      float psum = (ps[0] + ps[1]) + (ps[2] + ps[3]);
      psum += __shfl_xor(psum, 16, 64);
      psum += __shfl_xor(psum, 32, 64);
      lrun[m] = lrun[m] * alpha + psum;
      mrun[m] = mnew;
      float aB[4];
#pragma unroll
      for (int j = 0; j < 4; ++j) aB[j] = __shfl(alpha, lg * 4 + j, 64);
#pragma unroll
      for (int n = 0; n < 4; ++n)
#pragma unroll
        for (int j = 0; j < 4; ++j) oacc[m][n][j] *= aB[j];
      // ---- P read + PV for this m (vf transient per n) ----
      half8 pa[2];
#pragma unroll
      for (int ks = 0; ks < 2; ++ks) {
        int prow = m * 16 + lm;
        int byte = prow * 128 + ((ks * 64 + lg * 16) ^ ((prow & 7) << 4));
        pa[ks] = *(const half8*)(&Plds[w][byte]);
      }
#pragma unroll
      for (int n = 0; n < 4; ++n) {
        half8 vf0 = *(const half8*)&Vt[hb + (size_t)(n * 16 + lm) * 2048 + t * 64 + 0 * 32 + lg * 8];
        half8 vf1 = *(const half8*)&Vt[hb + (size_t)(n * 16 + lm) * 2048 + t * 64 + 1 * 32 + lg * 8];
        __builtin_amdgcn_s_setprio(1);
        oacc[m][n] = __builtin_amdgcn_mfma_f32_16x16x32_f16(pa[0], vf0, oacc[m][n], 0, 0, 0);
        oacc[m][n] = __builtin_amdgcn_mfma_f32_16x16x32_f16(pa[1], vf1, oacc[m][n], 0, 0, 0);
        __builtin_amdgcn_s_setprio(0);
      }
    }
  }
  int b = bh >> 4, h = bh & 15;
#pragma unroll
  for (int m = 0; m < 2; ++m) {
    float rinv = 1.0f / lrun[m];
    float rB[4];
#pragma unroll
    for (int j = 0; j < 4; ++j) rB[j] = __shfl(rinv, lg * 4 + j, 64);
#pragma unroll
    for (int n = 0; n < 4; ++n)
#pragma unroll
      for (int j = 0; j < 4; ++j) {
        float v = oacc[m][n][j] * rB[j];
        int sg = q0 + m * 16 + lg * 4 + j;
        int col = h * 64 + n * 16 + lm;
        out[((size_t)(b * 2048 + sg)) * 1024 + col] = (_Float16)v;
      }
  }
}

extern "C" void kernel_launch(void* const* d_in, const int* in_sizes, int n_in,
                              void* d_out, int out_size, void* d_ws, size_t ws_size,
                              hipStream_t stream) {
  const float* x = (const float*)d_in[0];
  const int* mask = (const int*)d_in[1];
  const float* Wq = (const float*)d_in[2];
  const float* bq = (const float*)d_in[3];
  const float* Wk = (const float*)d_in[4];
  const float* bk = (const float*)d_in[5];
  const float* Wv = (const float*)d_in[6];
  const float* bv = (const float*)d_in[7];
  const float* Wo = (const float*)d_in[8];
  const float* bo = (const float*)d_in[9];

  char* ws = (char*)d_ws;
  _Float16* xh = (_Float16*)(ws);                       // 16 MB, later reused as attn out
  _Float16* Wqh = (_Float16*)(ws + (16ull << 20));      // 2 MB
  _Float16* Wkh = (_Float16*)(ws + (18ull << 20));      // 2 MB
  _Float16* Wvh = (_Float16*)(ws + (20ull << 20));      // 2 MB
  _Float16* Woh = (_Float16*)(ws + (22ull << 20));      // 2 MB
  _Float16* Vt = (_Float16*)(ws + (24ull << 20));       // 16 MB
  unsigned char* flags = (unsigned char*)(ws + (40ull << 20));  // 512 B
  // Q and K scratch live inside d_out (32 MB fp32), fully overwritten by final GEMM
  _Float16* Qw = (_Float16*)d_out;
  _Float16* Kw = (_Float16*)((char*)d_out + (16ull << 20));
  _Float16* Ah = xh;  // attention output reuses x-f16 region

  const float QSCALE = 0.125f * 1.4426950408889634f;  // 1/sqrt(64) * log2(e)

  cvt_f32_f16<<<8192, 256, 0, stream>>>(x, xh, 2097152);
  cvt_f32_f16<<<1024, 256, 0, stream>>>(Wq, Wqh, 262144);
  cvt_f32_f16<<<1024, 256, 0, stream>>>(Wk, Wkh, 262144);
  cvt_f32_f16<<<1024, 256, 0, stream>>>(Wv, Wvh, 262144);
  cvt_f32_f16<<<1024, 256, 0, stream>>>(Wo, Woh, 262144);
  mask_flags_k<<<dim3(16, 32), 256, 0, stream>>>(mask, flags);
  gemm_k<0><<<dim3(8, 64), 256, 0, stream>>>(xh, Wqh, bq, Qw, QSCALE);
  gemm_k<0><<<dim3(8, 64), 256, 0, stream>>>(xh, Wkh, bk, Kw, 1.0f);
  gemm_k<1><<<dim3(8, 64), 256, 0, stream>>>(xh, Wvh, bv, Vt, 1.0f);
  attn_k<<<dim3(64, 16), 256, 0, stream>>>(Qw, Kw, Vt, flags, mask, Ah);
  gemm_k<2><<<dim3(8, 64), 256, 0, stream>>>(Ah, Woh, bo, d_out, 1.0f);
}

// Round 7
// 393.515 us; speedup vs baseline: 1.4867x; 1.4867x over previous
//
#include <hip/hip_runtime.h>

typedef _Float16 half8 __attribute__((ext_vector_type(8)));
typedef _Float16 half4v __attribute__((ext_vector_type(4)));
typedef float f32x4 __attribute__((ext_vector_type(4)));

__device__ __forceinline__ void gld_lds16(const void* g, void* l) {
  __builtin_amdgcn_global_load_lds((const __attribute__((address_space(1))) void*)g,
                                   (__attribute__((address_space(3))) void*)l, 16, 0, 0);
}

// ---------------- fp32 -> f16 convert (vectorized) ----------------
__global__ void cvt_f32_f16(const float* __restrict__ src, _Float16* __restrict__ dst, int n4) {
  int i = blockIdx.x * 256 + threadIdx.x;
  if (i < n4) {
    float4 v = ((const float4*)src)[i];
    half4v h;
    h.x = (_Float16)v.x; h.y = (_Float16)v.y; h.z = (_Float16)v.z; h.w = (_Float16)v.w;
    ((half4v*)dst)[i] = h;
  }
}

// ---------------- mask tile flags: flag=1 iff no zeros in 128x64 tile ----------------
__global__ void mask_flags_k(const int* __restrict__ mask, unsigned char* __restrict__ flags) {
  int qt = blockIdx.x, kt = blockIdx.y; // 16 x 32
  __shared__ int allv;
  if (threadIdx.x == 0) allv = 1;
  __syncthreads();
  int ok = 1;
  for (int idx = threadIdx.x; idx < 128 * 64; idx += 256) {
    int qr = qt * 128 + (idx >> 6);
    int kc = kt * 64 + (idx & 63);
    ok &= (mask[(size_t)qr * 2048 + kc] != 0);
  }
  if (!ok) atomicAnd(&allv, 0);
  __syncthreads();
  if (threadIdx.x == 0) flags[qt * 32 + kt] = (unsigned char)allv;
}

// ---------------- GEMM: y[M=8192,N=1024] = A[M,1024] @ B[N,1024]^T + bias, * oscale ----------
// LAYOUT 0: f16 heads [b,h,s,d]   LAYOUT 1: f16 V^T [b,h,d,s]   LAYOUT 2: fp32 [row,col]
// XCD-aware remap (T1): linear wg -> xcd = wg&7 owns an 8x8 (m,n) tile block so A-panels
// and B-panels are shared within one XCD's L2 (working set 4MB). Bijective for 512 blocks.
template <int LAYOUT>
__global__ __launch_bounds__(256, 2) void gemm_k(const _Float16* __restrict__ A,
                                                 const _Float16* __restrict__ B,
                                                 const float* __restrict__ bias,
                                                 void* __restrict__ dst, float oscale) {
  __shared__ _Float16 Alds[128][32];
  __shared__ _Float16 Blds[128][32];
  int tid = threadIdx.x, w = tid >> 6, l = tid & 63;
  int lm = l & 15, lg = l >> 4;
  int wm = w >> 1, wn = w & 1;
  int wg = blockIdx.y * 8 + blockIdx.x;  // linear id, x fastest
  int xcd = wg & 7, j = wg >> 3;
  int m0 = (xcd * 8 + (j >> 3)) * 128, n0 = (j & 7) * 128;
  f32x4 acc[4][4] = {};
  for (int k0 = 0; k0 < 1024; k0 += 32) {
#pragma unroll
    for (int c = 0; c < 2; ++c) {
      int o = w * 2048 + c * 1024 + l * 16;  // byte offset within 8KB tile
      int row = o >> 6;
      int kb = (o & 63) >> 1;  // f16 element offset within row
      gld_lds16(A + (size_t)(m0 + row) * 1024 + k0 + kb, (char*)&Alds[0][0] + w * 2048 + c * 1024);
      gld_lds16(B + (size_t)(n0 + row) * 1024 + k0 + kb, (char*)&Blds[0][0] + w * 2048 + c * 1024);
    }
    __syncthreads();
    half8 af[4], bf[4];
#pragma unroll
    for (int m = 0; m < 4; ++m) af[m] = *(const half8*)&Alds[wm * 64 + m * 16 + lm][lg * 8];
#pragma unroll
    for (int n = 0; n < 4; ++n) bf[n] = *(const half8*)&Blds[wn * 64 + n * 16 + lm][lg * 8];
#pragma unroll
    for (int m = 0; m < 4; ++m)
#pragma unroll
      for (int n = 0; n < 4; ++n)
        acc[m][n] = __builtin_amdgcn_mfma_f32_16x16x32_f16(af[m], bf[n], acc[m][n], 0, 0, 0);
    __syncthreads();
  }
  float bs[4];
#pragma unroll
  for (int n = 0; n < 4; ++n) bs[n] = bias[n0 + wn * 64 + n * 16 + lm];
#pragma unroll
  for (int m = 0; m < 4; ++m) {
#pragma unroll
    for (int n = 0; n < 4; ++n) {
      int colg = n0 + wn * 64 + n * 16 + lm;
#pragma unroll
      for (int j2 = 0; j2 < 4; ++j2) {
        int rowg = m0 + wm * 64 + m * 16 + lg * 4 + j2;
        float v = (acc[m][n][j2] + bs[n]) * oscale;
        if constexpr (LAYOUT == 0) {
          int b = rowg >> 11, s = rowg & 2047, h = colg >> 6, d = colg & 63;
          ((_Float16*)dst)[((size_t)(b * 16 + h) * 2048 + s) * 64 + d] = (_Float16)v;
        } else if constexpr (LAYOUT == 1) {
          int b = rowg >> 11, s = rowg & 2047, h = colg >> 6, d = colg & 63;
          ((_Float16*)dst)[((size_t)(b * 16 + h) * 64 + d) * 2048 + s] = (_Float16)v;
        } else {
          ((float*)dst)[(size_t)rowg * 1024 + colg] = v;
        }
      }
    }
  }
}

// ---------------- flash attention ----------------
// grid (64 bh, 16 qtiles) — x = bh so linear%8 = bh%8: all 16 q-tile blocks of one
// (b,h) land on the same XCD (T1). 256 threads = 4 waves; wave w owns 32 q-rows.
// Q pre-scaled by 0.125*log2(e) in its GEMM epilogue -> softmax in log2 domain.
// Swapped QK^T: sT = mfma(K, Q), lane owns q-row lm.
// ROUND 7: full-width body (round-4 structure) with __launch_bounds__(256,3):
// rounds 5/6 showed lb(256,4) pins the allocator at 64 VGPR -> permanent inner-loop
// spill (FETCH 524MB was scratch; all pipes <30%). Live set ~120 fits the ~168 cap
// of 3 waves/EU with margin; 3 waves/SIMD still beats round 2's 2.
__global__ __launch_bounds__(256, 3) void attn_k(const _Float16* __restrict__ Q,
                                                 const _Float16* __restrict__ K,
                                                 const _Float16* __restrict__ Vt,
                                                 const unsigned char* __restrict__ flags,
                                                 const int* __restrict__ mask,
                                                 _Float16* __restrict__ out) {
  __shared__ __align__(16) char Plds[4][4096];  // per-wave 32 rows x 128B, XOR-swizzled
  int bh = blockIdx.x, qt = blockIdx.y;
  int tid = threadIdx.x, w = tid >> 6, l = tid & 63;
  int lm = l & 15, lg = l >> 4;
  const size_t hb = (size_t)bh * (2048 * 64);
  int q0 = qt * 128 + w * 32;

  half8 qf[2][2];
#pragma unroll
  for (int m = 0; m < 2; ++m)
#pragma unroll
    for (int kk = 0; kk < 2; ++kk)
      qf[m][kk] = *(const half8*)&Q[hb + (size_t)(q0 + m * 16 + lm) * 64 + kk * 32 + lg * 8];

  f32x4 oacc[2][4] = {};
  float mrun[2] = {-1e30f, -1e30f};
  float lrun[2] = {0.f, 0.f};

  for (int t = 0; t < 32; ++t) {
    int flg = flags[qt * 32 + t];
    half8 kf[4][2];
#pragma unroll
    for (int n = 0; n < 4; ++n)
#pragma unroll
      for (int kk = 0; kk < 2; ++kk)
        kf[n][kk] = *(const half8*)&K[hb + (size_t)(t * 64 + n * 16 + lm) * 64 + kk * 32 + lg * 8];
    f32x4 sT[2][4];
    f32x4 z = {0.f, 0.f, 0.f, 0.f};
    __builtin_amdgcn_s_setprio(1);
#pragma unroll
    for (int m = 0; m < 2; ++m)
#pragma unroll
      for (int n = 0; n < 4; ++n) {
        sT[m][n] = __builtin_amdgcn_mfma_f32_16x16x32_f16(kf[n][0], qf[m][0], z, 0, 0, 0);
        sT[m][n] = __builtin_amdgcn_mfma_f32_16x16x32_f16(kf[n][1], qf[m][1], sT[m][n], 0, 0, 0);
      }
    __builtin_amdgcn_s_setprio(0);
    if (!flg) {  // slow path: per-element mask (not taken for all-ones mask)
#pragma unroll
      for (int m = 0; m < 2; ++m)
#pragma unroll
        for (int n = 0; n < 4; ++n)
#pragma unroll
          for (int j = 0; j < 4; ++j) {
            int qr = q0 + m * 16 + lm;
            int kc = t * 64 + n * 16 + lg * 4 + j;
            if (mask[(size_t)qr * 2048 + kc] == 0) sT[m][n][j] = -1e30f;
          }
    }
    float aB[2][4];
#pragma unroll
    for (int m = 0; m < 2; ++m) {
      float mx[4], ps[4];
#pragma unroll
      for (int n = 0; n < 4; ++n)
        mx[n] = fmaxf(fmaxf(sT[m][n][0], sT[m][n][1]), fmaxf(sT[m][n][2], sT[m][n][3]));
      float pmax = fmaxf(fmaxf(mx[0], mx[1]), fmaxf(mx[2], mx[3]));
      pmax = fmaxf(pmax, __shfl_xor(pmax, 16, 64));
      pmax = fmaxf(pmax, __shfl_xor(pmax, 32, 64));
      float mnew = fmaxf(mrun[m], pmax);
      float alpha = exp2f(mrun[m] - mnew);
      int row = m * 16 + lm;
#pragma unroll
      for (int n = 0; n < 4; ++n) {
        half4v p4;
        float pp[4];
#pragma unroll
        for (int j = 0; j < 4; ++j) {
          pp[j] = exp2f(sT[m][n][j] - mnew);  // log2-domain (L2E folded into Q)
          p4[j] = (_Float16)pp[j];
        }
        ps[n] = (pp[0] + pp[1]) + (pp[2] + pp[3]);
        int byte = row * 128 + (((n * 32 + lg * 8)) ^ ((row & 7) << 4));
        *(half4v*)(&Plds[w][byte]) = p4;
      }
      float psum = (ps[0] + ps[1]) + (ps[2] + ps[3]);
      psum += __shfl_xor(psum, 16, 64);
      psum += __shfl_xor(psum, 32, 64);
      lrun[m] = lrun[m] * alpha + psum;
      mrun[m] = mnew;
#pragma unroll
      for (int j = 0; j < 4; ++j) aB[m][j] = __shfl(alpha, lg * 4 + j, 64);
    }
#pragma unroll
    for (int m = 0; m < 2; ++m)
#pragma unroll
      for (int n = 0; n < 4; ++n)
#pragma unroll
        for (int j = 0; j < 4; ++j) oacc[m][n][j] *= aB[m][j];
    // read P as A-fragments (same swizzle), V^T fragments transient, PV MFMA
    half8 pa[2][2];
#pragma unroll
    for (int m = 0; m < 2; ++m)
#pragma unroll
      for (int ks = 0; ks < 2; ++ks) {
        int row = m * 16 + lm;
        int byte = row * 128 + ((ks * 64 + lg * 16) ^ ((row & 7) << 4));
        pa[m][ks] = *(const half8*)(&Plds[w][byte]);
      }
#pragma unroll
    for (int n = 0; n < 4; ++n) {
      half8 vf0 = *(const half8*)&Vt[hb + (size_t)(n * 16 + lm) * 2048 + t * 64 + 0 * 32 + lg * 8];
      half8 vf1 = *(const half8*)&Vt[hb + (size_t)(n * 16 + lm) * 2048 + t * 64 + 1 * 32 + lg * 8];
      __builtin_amdgcn_s_setprio(1);
#pragma unroll
      for (int m = 0; m < 2; ++m) {
        oacc[m][n] = __builtin_amdgcn_mfma_f32_16x16x32_f16(pa[m][0], vf0, oacc[m][n], 0, 0, 0);
        oacc[m][n] = __builtin_amdgcn_mfma_f32_16x16x32_f16(pa[m][1], vf1, oacc[m][n], 0, 0, 0);
      }
      __builtin_amdgcn_s_setprio(0);
    }
  }
  int b = bh >> 4, h = bh & 15;
#pragma unroll
  for (int m = 0; m < 2; ++m) {
    float rinv = 1.0f / lrun[m];
    float rB[4];
#pragma unroll
    for (int j = 0; j < 4; ++j) rB[j] = __shfl(rinv, lg * 4 + j, 64);
#pragma unroll
    for (int n = 0; n < 4; ++n)
#pragma unroll
      for (int j = 0; j < 4; ++j) {
        float v = oacc[m][n][j] * rB[j];
        int sg = q0 + m * 16 + lg * 4 + j;
        int col = h * 64 + n * 16 + lm;
        out[((size_t)(b * 2048 + sg)) * 1024 + col] = (_Float16)v;
      }
  }
}

extern "C" void kernel_launch(void* const* d_in, const int* in_sizes, int n_in,
                              void* d_out, int out_size, void* d_ws, size_t ws_size,
                              hipStream_t stream) {
  const float* x = (const float*)d_in[0];
  const int* mask = (const int*)d_in[1];
  const float* Wq = (const float*)d_in[2];
  const float* bq = (const float*)d_in[3];
  const float* Wk = (const float*)d_in[4];
  const float* bk = (const float*)d_in[5];
  const float* Wv = (const float*)d_in[6];
  const float* bv = (const float*)d_in[7];
  const float* Wo = (const float*)d_in[8];
  const float* bo = (const float*)d_in[9];

  char* ws = (char*)d_ws;
  _Float16* xh = (_Float16*)(ws);                       // 16 MB, later reused as attn out
  _Float16* Wqh = (_Float16*)(ws + (16ull << 20));      // 2 MB
  _Float16* Wkh = (_Float16*)(ws + (18ull << 20));      // 2 MB
  _Float16* Wvh = (_Float16*)(ws + (20ull << 20));      // 2 MB
  _Float16* Woh = (_Float16*)(ws + (22ull << 20));      // 2 MB
  _Float16* Vt = (_Float16*)(ws + (24ull << 20));       // 16 MB
  unsigned char* flags = (unsigned char*)(ws + (40ull << 20));  // 512 B
  // Q and K scratch live inside d_out (32 MB fp32), fully overwritten by final GEMM
  _Float16* Qw = (_Float16*)d_out;
  _Float16* Kw = (_Float16*)((char*)d_out + (16ull << 20));
  _Float16* Ah = xh;  // attention output reuses x-f16 region

  const float QSCALE = 0.125f * 1.4426950408889634f;  // 1/sqrt(64) * log2(e)

  cvt_f32_f16<<<8192, 256, 0, stream>>>(x, xh, 2097152);
  cvt_f32_f16<<<1024, 256, 0, stream>>>(Wq, Wqh, 262144);
  cvt_f32_f16<<<1024, 256, 0, stream>>>(Wk, Wkh, 262144);
  cvt_f32_f16<<<1024, 256, 0, stream>>>(Wv, Wvh, 262144);
  cvt_f32_f16<<<1024, 256, 0, stream>>>(Wo, Woh, 262144);
  mask_flags_k<<<dim3(16, 32), 256, 0, stream>>>(mask, flags);
  gemm_k<0><<<dim3(8, 64), 256, 0, stream>>>(xh, Wqh, bq, Qw, QSCALE);
  gemm_k<0><<<dim3(8, 64), 256, 0, stream>>>(xh, Wkh, bk, Kw, 1.0f);
  gemm_k<1><<<dim3(8, 64), 256, 0, stream>>>(xh, Wvh, bv, Vt, 1.0f);
  attn_k<<<dim3(64, 16), 256, 0, stream>>>(Qw, Kw, Vt, flags, mask, Ah);
  gemm_k<2><<<dim3(8, 64), 256, 0, stream>>>(Ah, Woh, bo, d_out, 1.0f);
}